// Round 7
// baseline (242.979 us; speedup 1.0000x reference)
//
#include <hip/hip_runtime.h>
#include <hip/hip_bf16.h>
#include <math.h>

// Problem constants (fixed by the reference)
#define NNODES 4096
#define NFEAT_ 1024
#define NHID_  64
#define NHEADS_ 8
#define EMB_   512
#define MAXD   256
constexpr float ALPHA_ = 0.2f;

typedef __attribute__((ext_vector_type(8))) short bf16x8;  // 8 bf16 (4 VGPRs)
typedef __attribute__((ext_vector_type(4))) float f32x4;   // MFMA accumulator
typedef unsigned int u32;
typedef unsigned short u16;

__device__ inline u16 f2b(float f) {
    __hip_bfloat16 b = __float2bfloat16(f);
    return *(u16*)&b;
}
__device__ inline float b2f(u16 u) {
    return __uint_as_float(((u32)u) << 16);
}

// async global->LDS, 16 B per lane. LDS dest: wave-uniform base + lane*16.
__device__ inline void cp16(const void* g, void* l) {
    __builtin_amdgcn_global_load_lds(
        (const __attribute__((address_space(1))) u32*)g,
        (__attribute__((address_space(3))) u32*)l, 16, 0, 0);
}

// ---------------------------------------------------------------------------
// bf16 MFMA GEMM:  C[M,N] = act( A[M,K] @ B[N,K]^T + bias )
// A, B bf16 row-major (B in B^T form). BM=128, 4 waves (2x2), double-buffered
// LDS: stage(next) issued before compute(cur), one __syncthreads per K-step.
// OUTM: 0 = fp32 out, 1 = bf16 out.   ACT: 1 = relu.
// SCORES (requires BN==64): block owns (head h = n0/64, rows m0..m0+128);
// epilogue computes es (row-dot a1) and edT[row][h] (row-dot a2) from the
// fp32 accumulators.
// M%128==0, N%BN==0, K%32==0 at every call site.
// ---------------------------------------------------------------------------
template<int BN, int OUTM, int ACT, bool SCORES>
__global__ __launch_bounds__(256) void gemm_bt(
    const u16* __restrict__ A, const u16* __restrict__ B,
    const float* __restrict__ bias, void* __restrict__ Cv,
    const float* __restrict__ a1, const float* __restrict__ a2,
    float* __restrict__ es, float* __restrict__ edT,
    int M, int N, int K)
{
    constexpr int BM  = 128, BK = 32;
    constexpr int WM  = BM / 2;       // wave row extent (64)
    constexpr int MI  = WM / 16;      // A fragments per wave (4)
    constexpr int WN  = BN / 2;       // wave column extent
    constexpr int NJ  = WN / 16;      // B fragments per wave
    constexpr int BCH = BN / 16;      // B 1KB chunks per K-tile (2,4,8)
    static_assert(!SCORES || BN == 64, "SCORES assumes one head per block");

    __shared__ __align__(16) u16 As[2][BM * BK];
    __shared__ __align__(16) u16 Bs[2][BN * BK];
    __shared__ float s1Lds[SCORES ? 2 : 1][SCORES ? BM : 1];
    __shared__ float s2Lds[SCORES ? 2 : 1][SCORES ? BM : 1];

    const int tid  = threadIdx.x;
    const int wid  = tid >> 6, lane = tid & 63;
    const int wr   = wid >> 1, wc = wid & 1;
    const int m0   = blockIdx.y * BM, n0 = blockIdx.x * BN;
    const int frow = lane & 15, fk = (lane >> 4) * 8;
    const int lr   = lane >> 2, lc = (lane & 3) * 8;   // within-chunk row/col

    auto stage = [&](int buf, int k0) {
        const u16* gA = A + (long)m0 * K + k0;
        int c = wid;
        cp16(gA + (long)(c * 16 + lr) * K + lc, &As[buf][c * 512]);
        c = wid + 4;
        cp16(gA + (long)(c * 16 + lr) * K + lc, &As[buf][c * 512]);
        const u16* gB = B + (long)n0 * K + k0;
        if (BCH >= 4) {
            c = wid;
            cp16(gB + (long)(c * 16 + lr) * K + lc, &Bs[buf][c * 512]);
            if (BCH == 8) {
                c = wid + 4;
                cp16(gB + (long)(c * 16 + lr) * K + lc, &Bs[buf][c * 512]);
            }
        } else if (wid < BCH) {
            cp16(gB + (long)(wid * 16 + lr) * K + lc, &Bs[buf][wid * 512]);
        }
    };

    f32x4 acc[MI][NJ] = {};

    stage(0, 0);
    __syncthreads();                  // drains vmcnt(0) before barrier
    int cur = 0;
    for (int k0 = 0; k0 < K; k0 += BK) {
        if (k0 + BK < K) stage(cur ^ 1, k0 + BK);   // overlap with compute

        bf16x8 af[MI], bfr[NJ];
        #pragma unroll
        for (int i = 0; i < MI; ++i)
            af[i] = *(const bf16x8*)&As[cur][(wr * WM + i * 16 + frow) * BK + fk];
        #pragma unroll
        for (int j = 0; j < NJ; ++j)
            bfr[j] = *(const bf16x8*)&Bs[cur][(wc * WN + j * 16 + frow) * BK + fk];
        #pragma unroll
        for (int i = 0; i < MI; ++i)
            #pragma unroll
            for (int j = 0; j < NJ; ++j)
                acc[i][j] = __builtin_amdgcn_mfma_f32_16x16x32_bf16(
                    af[i], bfr[j], acc[i][j], 0, 0, 0);

        __syncthreads();              // next tile staged + cur reads done
        cur ^= 1;
    }

    // epilogue: C/D layout col=lane&15, row=(lane>>4)*4+reg  [m89-verified]
    const int crow0 = m0 + wr * WM + (lane >> 4) * 4;
    const int ccol0 = n0 + wc * WN + (lane & 15);
    #pragma unroll
    for (int i = 0; i < MI; ++i)
        #pragma unroll
        for (int j = 0; j < NJ; ++j)
            #pragma unroll
            for (int r = 0; r < 4; ++r) {
                const int row = crow0 + i * 16 + r;
                const int col = ccol0 + j * 16;
                float v = acc[i][j][r];
                if (bias) v += bias[col];
                if (ACT == 1) v = v > 0.f ? v : 0.f;
                if (OUTM == 1) ((u16*)Cv)[(long)row * N + col] = f2b(v);
                else           ((float*)Cv)[(long)row * N + col] = v;
            }

    if constexpr (SCORES) {
        // e_src/e_dst for this block's (head, 128 rows) from fp32 accumulators
        const int h = n0 >> 6;
        const float a1v0 = a1[h * 64 + wc * WN + frow];
        const float a1v1 = a1[h * 64 + wc * WN + 16 + frow];
        const float a2v0 = a2[h * 64 + wc * WN + frow];
        const float a2v1 = a2[h * 64 + wc * WN + 16 + frow];
        #pragma unroll
        for (int i = 0; i < MI; ++i)
            #pragma unroll
            for (int r = 0; r < 4; ++r) {
                float s1 = acc[i][0][r] * a1v0 + acc[i][1][r] * a1v1;
                float s2 = acc[i][0][r] * a2v0 + acc[i][1][r] * a2v1;
                #pragma unroll
                for (int off = 8; off; off >>= 1) {
                    s1 += __shfl_xor(s1, off);
                    s2 += __shfl_xor(s2, off);
                }
                if (frow == 0) {
                    const int row = wr * WM + i * 16 + (lane >> 4) * 4 + r;
                    s1Lds[wc][row] = s1;
                    s2Lds[wc][row] = s2;
                }
            }
        __syncthreads();
        if (tid < BM) {
            es[h * NNODES + m0 + tid] = s1Lds[0][tid] + s1Lds[1][tid];
            edT[(m0 + tid) * NHEADS_ + h] = s2Lds[0][tid] + s2Lds[1][tid];
        }
    }
}

// ---------------------------------------------------------------------------
// Fused prep + neighbor-list build.
//   blocks [0, 4096)      : build_nbr row b from dense adjacency (float4 scan)
//   blocks [4096, 4224)   : WcT LDS tile-transpose (8 heads x 16 k-tiles)
//   blocks [4224, 4480)   : bf16 casts of x and decoder weights (grid-stride)
// ---------------------------------------------------------------------------
__global__ __launch_bounds__(256) void prep_nbr(
    const float* __restrict__ x,   const float* __restrict__ adj,
    const float* __restrict__ W,
    const float* __restrict__ W1,  const float* __restrict__ W2,
    const float* __restrict__ W3,  const float* __restrict__ W4,
    u16* __restrict__ xb,  u16* __restrict__ WcT,
    u16* __restrict__ W1b, u16* __restrict__ W2b,
    u16* __restrict__ W3b, u16* __restrict__ W4b,
    int* __restrict__ cnt, int* __restrict__ nbr)
{
    const int b = blockIdx.x, tid = threadIdx.x;

    if (b < NNODES) {
        // ---- neighbor list for row b ----
        __shared__ int lcnt;
        if (tid == 0) lcnt = 0;
        __syncthreads();
        const float4* arow = (const float4*)(adj + (long)b * NNODES);
        for (int m4 = tid; m4 < NNODES / 4; m4 += 256) {
            const float4 v = arow[m4];
            if (v.x != 0.f) { const int p = atomicAdd(&lcnt, 1); if (p < MAXD) nbr[b * MAXD + p] = m4 * 4; }
            if (v.y != 0.f) { const int p = atomicAdd(&lcnt, 1); if (p < MAXD) nbr[b * MAXD + p] = m4 * 4 + 1; }
            if (v.z != 0.f) { const int p = atomicAdd(&lcnt, 1); if (p < MAXD) nbr[b * MAXD + p] = m4 * 4 + 2; }
            if (v.w != 0.f) { const int p = atomicAdd(&lcnt, 1); if (p < MAXD) nbr[b * MAXD + p] = m4 * 4 + 3; }
        }
        __syncthreads();
        if (tid == 0) cnt[b] = lcnt < MAXD ? lcnt : MAXD;
    } else if (b < NNODES + 128) {
        // ---- WcT[h*64+d][k] = W[h][k][d], 64x64 tile via LDS ----
        __shared__ float tile[64][65];
        const int tb = b - NNODES;
        const int h = tb >> 4, k0 = (tb & 15) * 64;
        #pragma unroll
        for (int p = 0; p < 4; ++p) {
            const int kr = p * 16 + (tid >> 4), d = (tid & 15) * 4;
            const float4 v = *(const float4*)&W[((long)h * NFEAT_ + k0 + kr) * NHID_ + d];
            tile[kr][d] = v.x; tile[kr][d + 1] = v.y;
            tile[kr][d + 2] = v.z; tile[kr][d + 3] = v.w;
        }
        __syncthreads();
        #pragma unroll
        for (int p = 0; p < 4; ++p) {
            const int d = p * 16 + (tid >> 4), k = (tid & 15) * 4;
            ushort4 o;
            o.x = f2b(tile[k][d]);     o.y = f2b(tile[k + 1][d]);
            o.z = f2b(tile[k + 2][d]); o.w = f2b(tile[k + 3][d]);
            *(ushort4*)&WcT[((long)h * 64 + d) * NFEAT_ + k0 + k] = o;
        }
    } else {
        // ---- bf16 casts, grid-stride over 256 blocks ----
        const int np = 256 * 256;
        const int t = (b - NNODES - 128) * 256 + tid;
        for (int i = t; i < (NNODES * NFEAT_) / 4; i += np) {
            const float4 v = ((const float4*)x)[i];
            ushort4 o; o.x = f2b(v.x); o.y = f2b(v.y); o.z = f2b(v.z); o.w = f2b(v.w);
            ((ushort4*)xb)[i] = o;
        }
        for (int i = t; i < (256 * 512) / 4; i += np) {
            const float4 v = ((const float4*)W1)[i];
            ushort4 o; o.x = f2b(v.x); o.y = f2b(v.y); o.z = f2b(v.z); o.w = f2b(v.w);
            ((ushort4*)W1b)[i] = o;
        }
        for (int i = t; i < (256 * 256) / 4; i += np) {
            const float4 v = ((const float4*)W2)[i];
            ushort4 o; o.x = f2b(v.x); o.y = f2b(v.y); o.z = f2b(v.z); o.w = f2b(v.w);
            ((ushort4*)W2b)[i] = o;
        }
        for (int i = t; i < (512 * 256) / 4; i += np) {
            const float4 v = ((const float4*)W3)[i];
            ushort4 o; o.x = f2b(v.x); o.y = f2b(v.y); o.z = f2b(v.z); o.w = f2b(v.w);
            ((ushort4*)W3b)[i] = o;
        }
        for (int i = t; i < (1024 * 512) / 4; i += np) {
            const float4 v = ((const float4*)W4)[i];
            ushort4 o; o.x = f2b(v.x); o.y = f2b(v.y); o.z = f2b(v.z); o.w = f2b(v.w);
            ((ushort4*)W4b)[i] = o;
        }
    }
}

// ---------------------------------------------------------------------------
// Sparse masked softmax + aggregation + ELU -> enc (bf16, [N, H*nhid]).
// One block per node n (512 threads = 8 waves, wave h = head h):
//   - neighbor list loaded into LDS once per node (shared by all heads)
//   - e_dst gathered from edT[m][h]: the 8 waves' reads of neighbor m hit
//     the SAME 32B line
//   - phase 2: the 8 waves collectively consume each full 1KB Whb row
// Softmax fp32-exact; 16 gathers in flight per wave (lists padded with
// p=0/m=0 => exactly-zero contribution).
// ---------------------------------------------------------------------------
__global__ __launch_bounds__(512) void attn_agg(
    const u16* __restrict__ Whb, const float* __restrict__ esrc,
    const float* __restrict__ edT, const int* __restrict__ cnt,
    const int* __restrict__ nbr, u16* __restrict__ enc)
{
    __shared__ __align__(16) int   mLds[MAXD];
    __shared__ __align__(16) float pLds[NHEADS_][MAXD];
    const int h = threadIdx.x >> 6, lane = threadIdx.x & 63;
    const int n = blockIdx.x;

    const int deg  = min(cnt[n], MAXD);
    const int degp = (deg + 15) & ~15;           // padded length (<= MAXD)

    // wave 0: stage neighbor list (+ zero padding) into LDS
    if (h == 0) {
        const int* lst = nbr + n * MAXD;
        for (int j = lane; j < deg; j += 64) mLds[j] = lst[j];
        for (int j = deg + lane; j < degp; j += 64) mLds[j] = 0;
    }
    __syncthreads();

    const float es = esrc[h * NNODES + n];

    float mymax = -3.4e38f;
    for (int j = lane; j < deg; j += 64) {
        float ev = es + edT[mLds[j] * NHEADS_ + h];
        ev = ev > 0.f ? ev : ALPHA_ * ev;
        pLds[h][j] = ev;
        mymax = fmaxf(mymax, ev);
    }
    for (int j = deg + lane; j < degp; j += 64) pLds[h][j] = 0.f;
    #pragma unroll
    for (int off = 32; off; off >>= 1) mymax = fmaxf(mymax, __shfl_xor(mymax, off));

    float mysum = 0.f;
    for (int j = lane; j < deg; j += 64) {
        const float p = __expf(pLds[h][j] - mymax);
        pLds[h][j] = p;
        mysum += p;
    }
    #pragma unroll
    for (int off = 32; off; off >>= 1) mysum += __shfl_xor(mysum, off);

    __syncthreads();

    // Phase 2: lane == output dim d within head h. 16 gathers in flight.
    float acc = 0.f;
    const u16* base = Whb + h * NHID_ + lane;
    for (int j0 = 0; j0 < degp; j0 += 16) {
        const int4   ma = *(const int4*)&mLds[j0];
        const int4   mb = *(const int4*)&mLds[j0 + 4];
        const int4   mc = *(const int4*)&mLds[j0 + 8];
        const int4   md = *(const int4*)&mLds[j0 + 12];
        const float4 pa = *(const float4*)&pLds[h][j0];
        const float4 pb = *(const float4*)&pLds[h][j0 + 4];
        const float4 pc = *(const float4*)&pLds[h][j0 + 8];
        const float4 pd = *(const float4*)&pLds[h][j0 + 12];
        const float v0  = b2f(base[(long)ma.x << 9]);
        const float v1  = b2f(base[(long)ma.y << 9]);
        const float v2  = b2f(base[(long)ma.z << 9]);
        const float v3  = b2f(base[(long)ma.w << 9]);
        const float v4  = b2f(base[(long)mb.x << 9]);
        const float v5  = b2f(base[(long)mb.y << 9]);
        const float v6  = b2f(base[(long)mb.z << 9]);
        const float v7  = b2f(base[(long)mb.w << 9]);
        const float v8  = b2f(base[(long)mc.x << 9]);
        const float v9  = b2f(base[(long)mc.y << 9]);
        const float v10 = b2f(base[(long)mc.z << 9]);
        const float v11 = b2f(base[(long)mc.w << 9]);
        const float v12 = b2f(base[(long)md.x << 9]);
        const float v13 = b2f(base[(long)md.y << 9]);
        const float v14 = b2f(base[(long)md.z << 9]);
        const float v15 = b2f(base[(long)md.w << 9]);
        acc = fmaf(pa.x, v0,  acc); acc = fmaf(pa.y, v1,  acc);
        acc = fmaf(pa.z, v2,  acc); acc = fmaf(pa.w, v3,  acc);
        acc = fmaf(pb.x, v4,  acc); acc = fmaf(pb.y, v5,  acc);
        acc = fmaf(pb.z, v6,  acc); acc = fmaf(pb.w, v7,  acc);
        acc = fmaf(pc.x, v8,  acc); acc = fmaf(pc.y, v9,  acc);
        acc = fmaf(pc.z, v10, acc); acc = fmaf(pc.w, v11, acc);
        acc = fmaf(pd.x, v12, acc); acc = fmaf(pd.y, v13, acc);
        acc = fmaf(pd.z, v14, acc); acc = fmaf(pd.w, v15, acc);
    }

    float hv = acc / mysum;
    hv = hv > 0.f ? hv : expm1f(hv);                       // ELU
    enc[(long)n * EMB_ + h * NHID_ + lane] = f2b(hv);
}

// ---------------------------------------------------------------------------
extern "C" void kernel_launch(void* const* d_in, const int* in_sizes, int n_in,
                              void* d_out, int out_size, void* d_ws, size_t ws_size,
                              hipStream_t stream)
{
    const float* x   = (const float*)d_in[0];
    const float* adj = (const float*)d_in[1];
    const float* W   = (const float*)d_in[2];
    const float* a1  = (const float*)d_in[3];
    const float* a2  = (const float*)d_in[4];
    const float* W1  = (const float*)d_in[5];
    const float* b1  = (const float*)d_in[6];
    const float* W2  = (const float*)d_in[7];
    const float* b2  = (const float*)d_in[8];
    const float* W3  = (const float*)d_in[9];
    const float* b3  = (const float*)d_in[10];
    const float* W4  = (const float*)d_in[11];
    const float* b4  = (const float*)d_in[12];
    float* out = (float*)d_out;

    // Workspace layout (16B-aligned offsets). dd1..dd3 alias xb (dead after
    // the head GEMM).
    float* es  = (float*)d_ws;                        //    32,768 f
    float* edT = es + 32768;                          //    32,768 f  [n][8]
    u16* Whb = (u16*)(edT + 32768);                   // 2,097,152 us (4 MB)
    u16* enc = Whb + 2097152;                         // 2,097,152 us
    u16* WcT = enc + 2097152;                         //   524,288 us
    u16* W1b = WcT + 524288;                          //   131,072 us
    u16* W2b = W1b + 131072;                          //    65,536 us
    u16* W3b = W2b + 65536;                           //   131,072 us
    u16* W4b = W3b + 131072;                          //   524,288 us
    int* cnt = (int*)(W4b + 524288);                  //     4,096 i
    int* nbr = cnt + 4096;                            // 1,048,576 i
    u16* xb  = (u16*)(nbr + 1048576);                 // 4,194,304 us (8 MB)
    u16* dd1 = xb;                                    // 1,048,576 us (alias)
    u16* dd2 = dd1 + 1048576;                         // 1,048,576 us
    u16* dd3 = dd2 + 1048576;                         // 2,097,152 us

    // 0) fused: neighbor lists + WcT transpose + bf16 casts
    prep_nbr<<<dim3(NNODES + 128 + 256), 256, 0, stream>>>(
        x, adj, W, W1, W2, W3, W4, xb, WcT, W1b, W2b, W3b, W4b, cnt, nbr);

    // 1) head GEMM -> Whb bf16 [n, h*64+d] + fused e_src / e_dst^T
    gemm_bt<64, 1, 0, true><<<dim3(8, 32), 256, 0, stream>>>(
        xb, WcT, nullptr, Whb, a1, a2, es, edT, NNODES, EMB_, NFEAT_);

    // 2) sparse softmax + aggregate + ELU -> enc (bf16); block per node
    attn_agg<<<dim3(NNODES), 512, 0, stream>>>(Whb, es, edT, cnt, nbr, enc);

    // 3) decoder MLP (y = x @ W^T + b), bf16 MFMA, fp32 accum
    gemm_bt<32, 1, 1, false><<<dim3(8, 32), 256, 0, stream>>>(
        enc, W1b, b1, dd1, nullptr, nullptr, nullptr, nullptr, NNODES, 256, 512);
    gemm_bt<32, 1, 1, false><<<dim3(8, 32), 256, 0, stream>>>(
        dd1, W2b, b2, dd2, nullptr, nullptr, nullptr, nullptr, NNODES, 256, 256);
    gemm_bt<64, 1, 1, false><<<dim3(8, 32), 256, 0, stream>>>(
        dd2, W3b, b3, dd3, nullptr, nullptr, nullptr, nullptr, NNODES, 512, 256);
    gemm_bt<128, 0, 0, false><<<dim3(8, 32), 256, 0, stream>>>(
        dd3, W4b, b4, out, nullptr, nullptr, nullptr, nullptr, NNODES, 1024, 512);
}

// Round 10
// 228.270 us; speedup vs baseline: 1.0644x; 1.0644x over previous
//
#include <hip/hip_runtime.h>
#include <hip/hip_bf16.h>
#include <math.h>

// Problem constants (fixed by the reference)
#define NNODES 4096
#define NFEAT_ 1024
#define NHID_  64
#define NHEADS_ 8
#define EMB_   512
#define MAXD   256
constexpr float ALPHA_ = 0.2f;

typedef __attribute__((ext_vector_type(8))) short bf16x8;  // 8 bf16 (4 VGPRs)
typedef __attribute__((ext_vector_type(4))) float f32x4;   // MFMA accumulator
typedef unsigned int u32;
typedef unsigned short u16;

__device__ inline u16 f2b(float f) {
    __hip_bfloat16 b = __float2bfloat16(f);
    return *(u16*)&b;
}
__device__ inline float b2f(u16 u) {
    return __uint_as_float(((u32)u) << 16);
}

// async global->LDS, 16 B per lane. LDS dest: wave-uniform base + lane*16.
__device__ inline void cp16(const void* g, void* l) {
    __builtin_amdgcn_global_load_lds(
        (const __attribute__((address_space(1))) u32*)g,
        (__attribute__((address_space(3))) u32*)l, 16, 0, 0);
}

// ---------------------------------------------------------------------------
// bf16 MFMA GEMM:  C[M,N] = act( A[M,K] @ B[N,K]^T + bias )
// A, B bf16 row-major (B in B^T form). 4 waves (2x2), double-buffered LDS:
// stage(next) issued before compute(cur), one __syncthreads per K-step.
// BM=64 keeps 512-block grids (2 blocks/CU = 2 waves/SIMD — r7 showed
// BM=128/256-block grids expose all latency at 1 wave/SIMD).
// OUTM: 0 = fp32 out, 1 = bf16 out.   ACT: 1 = relu.
// SCORES (requires BN==64): block owns (head h = n0/64, rows m0..m0+BM);
// epilogue computes es (row-dot a1) and edT[row][h] (row-dot a2) from the
// fp32 accumulators.
// M%BM==0, N%BN==0, K%32==0 at every call site.
// ---------------------------------------------------------------------------
template<int BM, int BN, int OUTM, int ACT, bool SCORES>
__global__ __launch_bounds__(256) void gemm_bt(
    const u16* __restrict__ A, const u16* __restrict__ B,
    const float* __restrict__ bias, void* __restrict__ Cv,
    const float* __restrict__ a1, const float* __restrict__ a2,
    float* __restrict__ es, float* __restrict__ edT,
    int M, int N, int K)
{
    constexpr int BK  = 32;
    constexpr int WM  = BM / 2;       // wave row extent
    constexpr int MI  = WM / 16;      // A fragments per wave
    constexpr int WN  = BN / 2;       // wave column extent
    constexpr int NJ  = WN / 16;      // B fragments per wave
    constexpr int ACH = BM / 16;      // A 1KB chunks per K-tile (4 or 8)
    constexpr int BCH = BN / 16;      // B 1KB chunks per K-tile (2,4,8)
    static_assert(!SCORES || BN == 64, "SCORES assumes one head per block");

    __shared__ __align__(16) u16 As[2][BM * BK];
    __shared__ __align__(16) u16 Bs[2][BN * BK];
    __shared__ float s1Lds[SCORES ? 2 : 1][SCORES ? BM : 1];
    __shared__ float s2Lds[SCORES ? 2 : 1][SCORES ? BM : 1];

    const int tid  = threadIdx.x;
    const int wid  = tid >> 6, lane = tid & 63;
    const int wr   = wid >> 1, wc = wid & 1;
    const int m0   = blockIdx.y * BM, n0 = blockIdx.x * BN;
    const int frow = lane & 15, fk = (lane >> 4) * 8;
    const int lr   = lane >> 2, lc = (lane & 3) * 8;   // within-chunk row/col

    auto stage = [&](int buf, int k0) {
        const u16* gA = A + (long)m0 * K + k0;
        {
            int c = wid;
            cp16(gA + (long)(c * 16 + lr) * K + lc, &As[buf][c * 512]);
            if (ACH == 8) {
                c = wid + 4;
                cp16(gA + (long)(c * 16 + lr) * K + lc, &As[buf][c * 512]);
            }
        }
        const u16* gB = B + (long)n0 * K + k0;
        if (BCH >= 4) {
            int c = wid;
            cp16(gB + (long)(c * 16 + lr) * K + lc, &Bs[buf][c * 512]);
            if (BCH == 8) {
                c = wid + 4;
                cp16(gB + (long)(c * 16 + lr) * K + lc, &Bs[buf][c * 512]);
            }
        } else if (wid < BCH) {
            cp16(gB + (long)(wid * 16 + lr) * K + lc, &Bs[buf][wid * 512]);
        }
    };

    f32x4 acc[MI][NJ] = {};

    stage(0, 0);
    __syncthreads();                  // drains vmcnt(0) before barrier
    int cur = 0;
    for (int k0 = 0; k0 < K; k0 += BK) {
        if (k0 + BK < K) stage(cur ^ 1, k0 + BK);   // overlap with compute

        bf16x8 af[MI], bfr[NJ];
        #pragma unroll
        for (int i = 0; i < MI; ++i)
            af[i] = *(const bf16x8*)&As[cur][(wr * WM + i * 16 + frow) * BK + fk];
        #pragma unroll
        for (int j = 0; j < NJ; ++j)
            bfr[j] = *(const bf16x8*)&Bs[cur][(wc * WN + j * 16 + frow) * BK + fk];
        #pragma unroll
        for (int i = 0; i < MI; ++i)
            #pragma unroll
            for (int j = 0; j < NJ; ++j)
                acc[i][j] = __builtin_amdgcn_mfma_f32_16x16x32_bf16(
                    af[i], bfr[j], acc[i][j], 0, 0, 0);

        __syncthreads();              // next tile staged + cur reads done
        cur ^= 1;
    }

    // epilogue: C/D layout col=lane&15, row=(lane>>4)*4+reg  [m89-verified]
    const int crow0 = m0 + wr * WM + (lane >> 4) * 4;
    const int ccol0 = n0 + wc * WN + (lane & 15);
    #pragma unroll
    for (int i = 0; i < MI; ++i)
        #pragma unroll
        for (int j = 0; j < NJ; ++j)
            #pragma unroll
            for (int r = 0; r < 4; ++r) {
                const int row = crow0 + i * 16 + r;
                const int col = ccol0 + j * 16;
                float v = acc[i][j][r];
                if (bias) v += bias[col];
                if (ACT == 1) v = v > 0.f ? v : 0.f;
                if (OUTM == 1) ((u16*)Cv)[(long)row * N + col] = f2b(v);
                else           ((float*)Cv)[(long)row * N + col] = v;
            }

    if constexpr (SCORES) {
        // e_src/e_dst for this block's (head, BM rows) from fp32 accumulators
        const int h = n0 >> 6;
        const float a1v0 = a1[h * 64 + wc * WN + frow];
        const float a1v1 = a1[h * 64 + wc * WN + 16 + frow];
        const float a2v0 = a2[h * 64 + wc * WN + frow];
        const float a2v1 = a2[h * 64 + wc * WN + 16 + frow];
        #pragma unroll
        for (int i = 0; i < MI; ++i)
            #pragma unroll
            for (int r = 0; r < 4; ++r) {
                float s1 = acc[i][0][r] * a1v0 + acc[i][1][r] * a1v1;
                float s2 = acc[i][0][r] * a2v0 + acc[i][1][r] * a2v1;
                #pragma unroll
                for (int off = 8; off; off >>= 1) {
                    s1 += __shfl_xor(s1, off);
                    s2 += __shfl_xor(s2, off);
                }
                if (frow == 0) {
                    const int row = wr * WM + i * 16 + (lane >> 4) * 4 + r;
                    s1Lds[wc][row] = s1;
                    s2Lds[wc][row] = s2;
                }
            }
        __syncthreads();
        if (tid < BM) {
            es[h * NNODES + m0 + tid] = s1Lds[0][tid] + s1Lds[1][tid];
            edT[(m0 + tid) * NHEADS_ + h] = s2Lds[0][tid] + s2Lds[1][tid];
        }
    }
}

// ---------------------------------------------------------------------------
// Fused prep + neighbor-list build. HEAVY, LONG-RUNNING blocks FIRST in the
// grid (dispatch order ~ block index): casts start immediately and overlap
// the 4096 short nbr blocks; the tail is uniform nbr blocks (load-balanced).
//   blocks [0, 512)       : bf16 casts of x and decoder weights (grid-stride)
//   blocks [512, 640)     : WcT LDS tile-transpose (8 heads x 16 k-tiles)
//   blocks [640, 4736)    : build_nbr row (b-640) from dense adjacency
// ---------------------------------------------------------------------------
#define CASTB 512
__global__ __launch_bounds__(256) void prep_nbr(
    const float* __restrict__ x,   const float* __restrict__ adj,
    const float* __restrict__ W,
    const float* __restrict__ W1,  const float* __restrict__ W2,
    const float* __restrict__ W3,  const float* __restrict__ W4,
    u16* __restrict__ xb,  u16* __restrict__ WcT,
    u16* __restrict__ W1b, u16* __restrict__ W2b,
    u16* __restrict__ W3b, u16* __restrict__ W4b,
    int* __restrict__ cnt, int* __restrict__ nbr)
{
    const int b = blockIdx.x, tid = threadIdx.x;

    if (b < CASTB) {
        // ---- bf16 casts, grid-stride over CASTB blocks ----
        const int np = CASTB * 256;
        const int t = b * 256 + tid;
        for (int i = t; i < (NNODES * NFEAT_) / 4; i += np) {
            const float4 v = ((const float4*)x)[i];
            ushort4 o; o.x = f2b(v.x); o.y = f2b(v.y); o.z = f2b(v.z); o.w = f2b(v.w);
            ((ushort4*)xb)[i] = o;
        }
        for (int i = t; i < (256 * 512) / 4; i += np) {
            const float4 v = ((const float4*)W1)[i];
            ushort4 o; o.x = f2b(v.x); o.y = f2b(v.y); o.z = f2b(v.z); o.w = f2b(v.w);
            ((ushort4*)W1b)[i] = o;
        }
        for (int i = t; i < (256 * 256) / 4; i += np) {
            const float4 v = ((const float4*)W2)[i];
            ushort4 o; o.x = f2b(v.x); o.y = f2b(v.y); o.z = f2b(v.z); o.w = f2b(v.w);
            ((ushort4*)W2b)[i] = o;
        }
        for (int i = t; i < (512 * 256) / 4; i += np) {
            const float4 v = ((const float4*)W3)[i];
            ushort4 o; o.x = f2b(v.x); o.y = f2b(v.y); o.z = f2b(v.z); o.w = f2b(v.w);
            ((ushort4*)W3b)[i] = o;
        }
        for (int i = t; i < (1024 * 512) / 4; i += np) {
            const float4 v = ((const float4*)W4)[i];
            ushort4 o; o.x = f2b(v.x); o.y = f2b(v.y); o.z = f2b(v.z); o.w = f2b(v.w);
            ((ushort4*)W4b)[i] = o;
        }
    } else if (b < CASTB + 128) {
        // ---- WcT[h*64+d][k] = W[h][k][d], 64x64 tile via LDS ----
        __shared__ float tile[64][65];
        const int tb = b - CASTB;
        const int h = tb >> 4, k0 = (tb & 15) * 64;
        #pragma unroll
        for (int p = 0; p < 4; ++p) {
            const int kr = p * 16 + (tid >> 4), d = (tid & 15) * 4;
            const float4 v = *(const float4*)&W[((long)h * NFEAT_ + k0 + kr) * NHID_ + d];
            tile[kr][d] = v.x; tile[kr][d + 1] = v.y;
            tile[kr][d + 2] = v.z; tile[kr][d + 3] = v.w;
        }
        __syncthreads();
        #pragma unroll
        for (int p = 0; p < 4; ++p) {
            const int d = p * 16 + (tid >> 4), k = (tid & 15) * 4;
            ushort4 o;
            o.x = f2b(tile[k][d]);     o.y = f2b(tile[k + 1][d]);
            o.z = f2b(tile[k + 2][d]); o.w = f2b(tile[k + 3][d]);
            *(ushort4*)&WcT[((long)h * 64 + d) * NFEAT_ + k0 + k] = o;
        }
    } else {
        // ---- neighbor list for row n = b - CASTB - 128 ----
        __shared__ int lcnt;
        const int n = b - CASTB - 128;
        if (tid == 0) lcnt = 0;
        __syncthreads();
        const float4* arow = (const float4*)(adj + (long)n * NNODES);
        for (int m4 = tid; m4 < NNODES / 4; m4 += 256) {
            const float4 v = arow[m4];
            if (v.x != 0.f) { const int p = atomicAdd(&lcnt, 1); if (p < MAXD) nbr[n * MAXD + p] = m4 * 4; }
            if (v.y != 0.f) { const int p = atomicAdd(&lcnt, 1); if (p < MAXD) nbr[n * MAXD + p] = m4 * 4 + 1; }
            if (v.z != 0.f) { const int p = atomicAdd(&lcnt, 1); if (p < MAXD) nbr[n * MAXD + p] = m4 * 4 + 2; }
            if (v.w != 0.f) { const int p = atomicAdd(&lcnt, 1); if (p < MAXD) nbr[n * MAXD + p] = m4 * 4 + 3; }
        }
        __syncthreads();
        if (tid == 0) cnt[n] = lcnt < MAXD ? lcnt : MAXD;
    }
}

// ---------------------------------------------------------------------------
// Sparse masked softmax + aggregation + ELU -> enc (bf16, [N, H*nhid]).
// One block per node n (512 threads = 8 waves, wave h = head h):
//   - neighbor list loaded into LDS once per node (shared by all heads)
//   - e_dst gathered from edT[m][h]: the 8 waves' reads of neighbor m hit
//     the SAME 32B line
//   - phase 2: the 8 waves collectively consume each full 1KB Whb row
// Softmax fp32-exact; 16 gathers in flight per wave (lists padded with
// p=0/m=0 => exactly-zero contribution).
// ---------------------------------------------------------------------------
__global__ __launch_bounds__(512) void attn_agg(
    const u16* __restrict__ Whb, const float* __restrict__ esrc,
    const float* __restrict__ edT, const int* __restrict__ cnt,
    const int* __restrict__ nbr, u16* __restrict__ enc)
{
    __shared__ __align__(16) int   mLds[MAXD];
    __shared__ __align__(16) float pLds[NHEADS_][MAXD];
    const int h = threadIdx.x >> 6, lane = threadIdx.x & 63;
    const int n = blockIdx.x;

    const int deg  = min(cnt[n], MAXD);
    const int degp = (deg + 15) & ~15;           // padded length (<= MAXD)

    // wave 0: stage neighbor list (+ zero padding) into LDS
    if (h == 0) {
        const int* lst = nbr + n * MAXD;
        for (int j = lane; j < deg; j += 64) mLds[j] = lst[j];
        for (int j = deg + lane; j < degp; j += 64) mLds[j] = 0;
    }
    __syncthreads();

    const float es = esrc[h * NNODES + n];

    float mymax = -3.4e38f;
    for (int j = lane; j < deg; j += 64) {
        float ev = es + edT[mLds[j] * NHEADS_ + h];
        ev = ev > 0.f ? ev : ALPHA_ * ev;
        pLds[h][j] = ev;
        mymax = fmaxf(mymax, ev);
    }
    for (int j = deg + lane; j < degp; j += 64) pLds[h][j] = 0.f;
    #pragma unroll
    for (int off = 32; off; off >>= 1) mymax = fmaxf(mymax, __shfl_xor(mymax, off));

    float mysum = 0.f;
    for (int j = lane; j < deg; j += 64) {
        const float p = __expf(pLds[h][j] - mymax);
        pLds[h][j] = p;
        mysum += p;
    }
    #pragma unroll
    for (int off = 32; off; off >>= 1) mysum += __shfl_xor(mysum, off);

    __syncthreads();

    // Phase 2: lane == output dim d within head h. 16 gathers in flight.
    float acc = 0.f;
    const u16* base = Whb + h * NHID_ + lane;
    for (int j0 = 0; j0 < degp; j0 += 16) {
        const int4   ma = *(const int4*)&mLds[j0];
        const int4   mb = *(const int4*)&mLds[j0 + 4];
        const int4   mc = *(const int4*)&mLds[j0 + 8];
        const int4   md = *(const int4*)&mLds[j0 + 12];
        const float4 pa = *(const float4*)&pLds[h][j0];
        const float4 pb = *(const float4*)&pLds[h][j0 + 4];
        const float4 pc = *(const float4*)&pLds[h][j0 + 8];
        const float4 pd = *(const float4*)&pLds[h][j0 + 12];
        const float v0  = b2f(base[(long)ma.x << 9]);
        const float v1  = b2f(base[(long)ma.y << 9]);
        const float v2  = b2f(base[(long)ma.z << 9]);
        const float v3  = b2f(base[(long)ma.w << 9]);
        const float v4  = b2f(base[(long)mb.x << 9]);
        const float v5  = b2f(base[(long)mb.y << 9]);
        const float v6  = b2f(base[(long)mb.z << 9]);
        const float v7  = b2f(base[(long)mb.w << 9]);
        const float v8  = b2f(base[(long)mc.x << 9]);
        const float v9  = b2f(base[(long)mc.y << 9]);
        const float v10 = b2f(base[(long)mc.z << 9]);
        const float v11 = b2f(base[(long)mc.w << 9]);
        const float v12 = b2f(base[(long)md.x << 9]);
        const float v13 = b2f(base[(long)md.y << 9]);
        const float v14 = b2f(base[(long)md.z << 9]);
        const float v15 = b2f(base[(long)md.w << 9]);
        acc = fmaf(pa.x, v0,  acc); acc = fmaf(pa.y, v1,  acc);
        acc = fmaf(pa.z, v2,  acc); acc = fmaf(pa.w, v3,  acc);
        acc = fmaf(pb.x, v4,  acc); acc = fmaf(pb.y, v5,  acc);
        acc = fmaf(pb.z, v6,  acc); acc = fmaf(pb.w, v7,  acc);
        acc = fmaf(pc.x, v8,  acc); acc = fmaf(pc.y, v9,  acc);
        acc = fmaf(pc.z, v10, acc); acc = fmaf(pc.w, v11, acc);
        acc = fmaf(pd.x, v12, acc); acc = fmaf(pd.y, v13, acc);
        acc = fmaf(pd.z, v14, acc); acc = fmaf(pd.w, v15, acc);
    }

    float hv = acc / mysum;
    hv = hv > 0.f ? hv : expm1f(hv);                       // ELU
    enc[(long)n * EMB_ + h * NHID_ + lane] = f2b(hv);
}

// ---------------------------------------------------------------------------
extern "C" void kernel_launch(void* const* d_in, const int* in_sizes, int n_in,
                              void* d_out, int out_size, void* d_ws, size_t ws_size,
                              hipStream_t stream)
{
    const float* x   = (const float*)d_in[0];
    const float* adj = (const float*)d_in[1];
    const float* W   = (const float*)d_in[2];
    const float* a1  = (const float*)d_in[3];
    const float* a2  = (const float*)d_in[4];
    const float* W1  = (const float*)d_in[5];
    const float* b1  = (const float*)d_in[6];
    const float* W2  = (const float*)d_in[7];
    const float* b2  = (const float*)d_in[8];
    const float* W3  = (const float*)d_in[9];
    const float* b3  = (const float*)d_in[10];
    const float* W4  = (const float*)d_in[11];
    const float* b4  = (const float*)d_in[12];
    float* out = (float*)d_out;

    // Workspace layout (16B-aligned offsets). dd1..dd3 alias xb (dead after
    // the head GEMM).
    float* es  = (float*)d_ws;                        //    32,768 f
    float* edT = es + 32768;                          //    32,768 f  [n][8]
    u16* Whb = (u16*)(edT + 32768);                   // 2,097,152 us (4 MB)
    u16* enc = Whb + 2097152;                         // 2,097,152 us
    u16* WcT = enc + 2097152;                         //   524,288 us
    u16* W1b = WcT + 524288;                          //   131,072 us
    u16* W2b = W1b + 131072;                          //    65,536 us
    u16* W3b = W2b + 65536;                           //   131,072 us
    u16* W4b = W3b + 131072;                          //   524,288 us
    int* cnt = (int*)(W4b + 524288);                  //     4,096 i
    int* nbr = cnt + 4096;                            // 1,048,576 i
    u16* xb  = (u16*)(nbr + 1048576);                 // 4,194,304 us (8 MB)
    u16* dd1 = xb;                                    // 1,048,576 us (alias)
    u16* dd2 = dd1 + 1048576;                         // 1,048,576 us
    u16* dd3 = dd2 + 1048576;                         // 2,097,152 us

    // 0) fused: bf16 casts (first = dispatched first) + WcT transpose +
    //    neighbor lists (uniform short blocks as the tail)
    prep_nbr<<<dim3(CASTB + 128 + NNODES), 256, 0, stream>>>(
        x, adj, W, W1, W2, W3, W4, xb, WcT, W1b, W2b, W3b, W4b, cnt, nbr);

    // 1) head GEMM -> Whb bf16 [n, h*64+d] + fused e_src / e_dst^T
    gemm_bt<64, 64, 1, 0, true><<<dim3(8, 64), 256, 0, stream>>>(
        xb, WcT, nullptr, Whb, a1, a2, es, edT, NNODES, EMB_, NFEAT_);

    // 2) sparse softmax + aggregate + ELU -> enc (bf16); block per node
    attn_agg<<<dim3(NNODES), 512, 0, stream>>>(Whb, es, edT, cnt, nbr, enc);

    // 3) decoder MLP (y = x @ W^T + b), bf16 MFMA, fp32 accum
    gemm_bt<64, 32, 1, 1, false><<<dim3(8, 64), 256, 0, stream>>>(
        enc, W1b, b1, dd1, nullptr, nullptr, nullptr, nullptr, NNODES, 256, 512);
    gemm_bt<64, 32, 1, 1, false><<<dim3(8, 64), 256, 0, stream>>>(
        dd1, W2b, b2, dd2, nullptr, nullptr, nullptr, nullptr, NNODES, 256, 256);
    gemm_bt<64, 64, 1, 1, false><<<dim3(8, 64), 256, 0, stream>>>(
        dd2, W3b, b3, dd3, nullptr, nullptr, nullptr, nullptr, NNODES, 512, 256);
    gemm_bt<128, 128, 0, 0, false><<<dim3(8, 32), 256, 0, stream>>>(
        dd3, W4b, b4, out, nullptr, nullptr, nullptr, nullptr, NNODES, 1024, 512);
}

// Round 14
// 222.125 us; speedup vs baseline: 1.0939x; 1.0277x over previous
//
#include <hip/hip_runtime.h>
#include <hip/hip_bf16.h>
#include <math.h>

// Problem constants (fixed by the reference)
#define NNODES 4096
#define NFEAT_ 1024
#define NHID_  64
#define NHEADS_ 8
#define EMB_   512
#define MAXD   256
constexpr float ALPHA_ = 0.2f;

typedef __attribute__((ext_vector_type(8))) short bf16x8;  // 8 bf16 (4 VGPRs)
typedef __attribute__((ext_vector_type(4))) float f32x4;   // MFMA accumulator
typedef unsigned int u32;
typedef unsigned short u16;

__device__ inline u16 f2b(float f) {
    __hip_bfloat16 b = __float2bfloat16(f);
    return *(u16*)&b;
}
__device__ inline float b2f(u16 u) {
    return __uint_as_float(((u32)u) << 16);
}

// async global->LDS, 16 B per lane. LDS dest: wave-uniform base + lane*16.
__device__ inline void cp16(const void* g, void* l) {
    __builtin_amdgcn_global_load_lds(
        (const __attribute__((address_space(1))) u32*)g,
        (__attribute__((address_space(3))) u32*)l, 16, 0, 0);
}

// ---------------------------------------------------------------------------
// Decoder bf16 MFMA GEMM:  C[M,N] = act( A[M,K] @ B[N,K]^T + bias )
// A, B bf16 row-major (B in B^T form). 4 waves (2x2), double-buffered LDS:
// stage(next) issued before compute(cur), one __syncthreads per K-step.
// BM=64 keeps >=512-block grids (2 blocks/CU = 2 waves/SIMD; r7 showed
// 256-block grids at 1 wave/SIMD expose all latency).
// OUTM: 0 = fp32 out, 1 = bf16 out.   ACT: 1 = relu.
// M%BM==0, N%BN==0, K%32==0 at every call site.
// ---------------------------------------------------------------------------
template<int BM, int BN, int OUTM, int ACT>
__global__ __launch_bounds__(256) void gemm_bt(
    const u16* __restrict__ A, const u16* __restrict__ B,
    const float* __restrict__ bias, void* __restrict__ Cv,
    int M, int N, int K)
{
    constexpr int BK  = 32;
    constexpr int WM  = BM / 2;       // wave row extent
    constexpr int MI  = WM / 16;      // A fragments per wave
    constexpr int WN  = BN / 2;       // wave column extent
    constexpr int NJ  = WN / 16;      // B fragments per wave
    constexpr int ACH = BM / 16;      // A 1KB chunks per K-tile (4 or 8)
    constexpr int BCH = BN / 16;      // B 1KB chunks per K-tile (2,4,8)

    __shared__ __align__(16) u16 As[2][BM * BK];
    __shared__ __align__(16) u16 Bs[2][BN * BK];

    const int tid  = threadIdx.x;
    const int wid  = tid >> 6, lane = tid & 63;
    const int wr   = wid >> 1, wc = wid & 1;
    const int m0   = blockIdx.y * BM, n0 = blockIdx.x * BN;
    const int frow = lane & 15, fk = (lane >> 4) * 8;
    const int lr   = lane >> 2, lc = (lane & 3) * 8;   // within-chunk row/col

    auto stage = [&](int buf, int k0) {
        const u16* gA = A + (long)m0 * K + k0;
        {
            int c = wid;
            cp16(gA + (long)(c * 16 + lr) * K + lc, &As[buf][c * 512]);
            if (ACH == 8) {
                c = wid + 4;
                cp16(gA + (long)(c * 16 + lr) * K + lc, &As[buf][c * 512]);
            }
        }
        const u16* gB = B + (long)n0 * K + k0;
        if (BCH >= 4) {
            int c = wid;
            cp16(gB + (long)(c * 16 + lr) * K + lc, &Bs[buf][c * 512]);
            if (BCH == 8) {
                c = wid + 4;
                cp16(gB + (long)(c * 16 + lr) * K + lc, &Bs[buf][c * 512]);
            }
        } else if (wid < BCH) {
            cp16(gB + (long)(wid * 16 + lr) * K + lc, &Bs[buf][wid * 512]);
        }
    };

    f32x4 acc[MI][NJ] = {};

    stage(0, 0);
    __syncthreads();                  // drains vmcnt(0) before barrier
    int cur = 0;
    for (int k0 = 0; k0 < K; k0 += BK) {
        if (k0 + BK < K) stage(cur ^ 1, k0 + BK);   // overlap with compute

        bf16x8 af[MI], bfr[NJ];
        #pragma unroll
        for (int i = 0; i < MI; ++i)
            af[i] = *(const bf16x8*)&As[cur][(wr * WM + i * 16 + frow) * BK + fk];
        #pragma unroll
        for (int j = 0; j < NJ; ++j)
            bfr[j] = *(const bf16x8*)&Bs[cur][(wc * WN + j * 16 + frow) * BK + fk];
        #pragma unroll
        for (int i = 0; i < MI; ++i)
            #pragma unroll
            for (int j = 0; j < NJ; ++j)
                acc[i][j] = __builtin_amdgcn_mfma_f32_16x16x32_bf16(
                    af[i], bfr[j], acc[i][j], 0, 0, 0);

        __syncthreads();              // next tile staged + cur reads done
        cur ^= 1;
    }

    // epilogue: C/D layout col=lane&15, row=(lane>>4)*4+reg  [m89-verified]
    const int crow0 = m0 + wr * WM + (lane >> 4) * 4;
    const int ccol0 = n0 + wc * WN + (lane & 15);
    #pragma unroll
    for (int i = 0; i < MI; ++i)
        #pragma unroll
        for (int j = 0; j < NJ; ++j)
            #pragma unroll
            for (int r = 0; r < 4; ++r) {
                const int row = crow0 + i * 16 + r;
                const int col = ccol0 + j * 16;
                float v = acc[i][j][r];
                if (bias) v += bias[col];
                if (ACT == 1) v = v > 0.f ? v : 0.f;
                if (OUTM == 1) ((u16*)Cv)[(long)row * N + col] = f2b(v);
                else           ((float*)Cv)[(long)row * N + col] = v;
            }
}

// ---------------------------------------------------------------------------
// Head GEMM (Whb = xb @ WcT^T, bf16 out, fused e_src/e_dst^T epilogue)
// FUSED with the neighbor-list build: the head GEMM does not depend on
// nbr/cnt, and the nbr scan is pure HBM while the GEMM is compute/L2-bound,
// so the 64 MB adjacency scan runs under the GEMM for free.
//   blocks [0, 512)      : GEMM tile (m0 = (b>>3)*64, n0 = (b&7)*64)
//   blocks [512, 4608)   : neighbor list for row b-512
// ---------------------------------------------------------------------------
__global__ __launch_bounds__(256) void head_gemm_nbr(
    const u16* __restrict__ A, const u16* __restrict__ B,
    u16* __restrict__ Whb,
    const float* __restrict__ a1, const float* __restrict__ a2,
    float* __restrict__ es, float* __restrict__ edT,
    const float* __restrict__ adj, int* __restrict__ cnt,
    int* __restrict__ nbr)
{
    constexpr int BM = 64, BN = 64, BK = 32;
    constexpr int WM = 32, MI = 2, WN = 32, NJ = 2;
    constexpr int M = NNODES, N = EMB_, K = NFEAT_;

    __shared__ __align__(16) u16 As[2][BM * BK];
    __shared__ __align__(16) u16 Bs[2][BN * BK];
    __shared__ float s1Lds[2][BM];
    __shared__ float s2Lds[2][BM];
    __shared__ int lcnt;

    const int bid = blockIdx.x;
    const int tid = threadIdx.x;

    if (bid >= 512) {
        // ---- neighbor list for row n = bid - 512 ----
        const int n = bid - 512;
        if (tid == 0) lcnt = 0;
        __syncthreads();
        const float4* arow = (const float4*)(adj + (long)n * NNODES);
        for (int m4 = tid; m4 < NNODES / 4; m4 += 256) {
            const float4 v = arow[m4];
            if (v.x != 0.f) { const int p = atomicAdd(&lcnt, 1); if (p < MAXD) nbr[n * MAXD + p] = m4 * 4; }
            if (v.y != 0.f) { const int p = atomicAdd(&lcnt, 1); if (p < MAXD) nbr[n * MAXD + p] = m4 * 4 + 1; }
            if (v.z != 0.f) { const int p = atomicAdd(&lcnt, 1); if (p < MAXD) nbr[n * MAXD + p] = m4 * 4 + 2; }
            if (v.w != 0.f) { const int p = atomicAdd(&lcnt, 1); if (p < MAXD) nbr[n * MAXD + p] = m4 * 4 + 3; }
        }
        __syncthreads();
        if (tid == 0) cnt[n] = lcnt < MAXD ? lcnt : MAXD;
        return;
    }

    // ---- GEMM tile ----
    const int wid  = tid >> 6, lane = tid & 63;
    const int wr   = wid >> 1, wc = wid & 1;
    const int m0   = (bid >> 3) * BM, n0 = (bid & 7) * BN;
    const int frow = lane & 15, fk = (lane >> 4) * 8;
    const int lr   = lane >> 2, lc = (lane & 3) * 8;

    auto stage = [&](int buf, int k0) {
        const u16* gA = A + (long)m0 * K + k0;
        cp16(gA + (long)(wid * 16 + lr) * K + lc, &As[buf][wid * 512]);
        const u16* gB = B + (long)n0 * K + k0;
        cp16(gB + (long)(wid * 16 + lr) * K + lc, &Bs[buf][wid * 512]);
    };

    f32x4 acc[MI][NJ] = {};

    stage(0, 0);
    __syncthreads();
    int cur = 0;
    for (int k0 = 0; k0 < K; k0 += BK) {
        if (k0 + BK < K) stage(cur ^ 1, k0 + BK);

        bf16x8 af[MI], bfr[NJ];
        #pragma unroll
        for (int i = 0; i < MI; ++i)
            af[i] = *(const bf16x8*)&As[cur][(wr * WM + i * 16 + frow) * BK + fk];
        #pragma unroll
        for (int j = 0; j < NJ; ++j)
            bfr[j] = *(const bf16x8*)&Bs[cur][(wc * WN + j * 16 + frow) * BK + fk];
        #pragma unroll
        for (int i = 0; i < MI; ++i)
            #pragma unroll
            for (int j = 0; j < NJ; ++j)
                acc[i][j] = __builtin_amdgcn_mfma_f32_16x16x32_bf16(
                    af[i], bfr[j], acc[i][j], 0, 0, 0);

        __syncthreads();
        cur ^= 1;
    }

    // epilogue: Whb bf16 write
    const int crow0 = m0 + wr * WM + (lane >> 4) * 4;
    const int ccol0 = n0 + wc * WN + (lane & 15);
    #pragma unroll
    for (int i = 0; i < MI; ++i)
        #pragma unroll
        for (int j = 0; j < NJ; ++j)
            #pragma unroll
            for (int r = 0; r < 4; ++r)
                Whb[(long)(crow0 + i * 16 + r) * N + ccol0 + j * 16] =
                    f2b(acc[i][j][r]);

    // fused e_src / e_dst^T from fp32 accumulators (head h = n0/64)
    const int h = n0 >> 6;
    const float a1v0 = a1[h * 64 + wc * WN + frow];
    const float a1v1 = a1[h * 64 + wc * WN + 16 + frow];
    const float a2v0 = a2[h * 64 + wc * WN + frow];
    const float a2v1 = a2[h * 64 + wc * WN + 16 + frow];
    #pragma unroll
    for (int i = 0; i < MI; ++i)
        #pragma unroll
        for (int r = 0; r < 4; ++r) {
            float s1 = acc[i][0][r] * a1v0 + acc[i][1][r] * a1v1;
            float s2 = acc[i][0][r] * a2v0 + acc[i][1][r] * a2v1;
            #pragma unroll
            for (int off = 8; off; off >>= 1) {
                s1 += __shfl_xor(s1, off);
                s2 += __shfl_xor(s2, off);
            }
            if (frow == 0) {
                const int row = wr * WM + i * 16 + (lane >> 4) * 4 + r;
                s1Lds[wc][row] = s1;
                s2Lds[wc][row] = s2;
            }
        }
    __syncthreads();
    if (tid < BM) {
        es[h * NNODES + m0 + tid] = s1Lds[0][tid] + s1Lds[1][tid];
        edT[(m0 + tid) * NHEADS_ + h] = s2Lds[0][tid] + s2Lds[1][tid];
    }
}

// ---------------------------------------------------------------------------
// Prep: bf16 casts of x / decoder weights + WcT tile-transpose.
//   blocks [0, 512)   : casts (grid-stride)
//   blocks [512, 640) : WcT[h*64+d][k] = W[h][k][d] (64x64 LDS transpose)
// ---------------------------------------------------------------------------
#define CASTB 512
__global__ __launch_bounds__(256) void prep(
    const float* __restrict__ x,   const float* __restrict__ W,
    const float* __restrict__ W1,  const float* __restrict__ W2,
    const float* __restrict__ W3,  const float* __restrict__ W4,
    u16* __restrict__ xb,  u16* __restrict__ WcT,
    u16* __restrict__ W1b, u16* __restrict__ W2b,
    u16* __restrict__ W3b, u16* __restrict__ W4b)
{
    const int b = blockIdx.x, tid = threadIdx.x;

    if (b < CASTB) {
        const int np = CASTB * 256;
        const int t = b * 256 + tid;
        for (int i = t; i < (NNODES * NFEAT_) / 4; i += np) {
            const float4 v = ((const float4*)x)[i];
            ushort4 o; o.x = f2b(v.x); o.y = f2b(v.y); o.z = f2b(v.z); o.w = f2b(v.w);
            ((ushort4*)xb)[i] = o;
        }
        for (int i = t; i < (256 * 512) / 4; i += np) {
            const float4 v = ((const float4*)W1)[i];
            ushort4 o; o.x = f2b(v.x); o.y = f2b(v.y); o.z = f2b(v.z); o.w = f2b(v.w);
            ((ushort4*)W1b)[i] = o;
        }
        for (int i = t; i < (256 * 256) / 4; i += np) {
            const float4 v = ((const float4*)W2)[i];
            ushort4 o; o.x = f2b(v.x); o.y = f2b(v.y); o.z = f2b(v.z); o.w = f2b(v.w);
            ((ushort4*)W2b)[i] = o;
        }
        for (int i = t; i < (512 * 256) / 4; i += np) {
            const float4 v = ((const float4*)W3)[i];
            ushort4 o; o.x = f2b(v.x); o.y = f2b(v.y); o.z = f2b(v.z); o.w = f2b(v.w);
            ((ushort4*)W3b)[i] = o;
        }
        for (int i = t; i < (1024 * 512) / 4; i += np) {
            const float4 v = ((const float4*)W4)[i];
            ushort4 o; o.x = f2b(v.x); o.y = f2b(v.y); o.z = f2b(v.z); o.w = f2b(v.w);
            ((ushort4*)W4b)[i] = o;
        }
    } else {
        __shared__ float tile[64][65];
        const int tb = b - CASTB;
        const int h = tb >> 4, k0 = (tb & 15) * 64;
        #pragma unroll
        for (int p = 0; p < 4; ++p) {
            const int kr = p * 16 + (tid >> 4), d = (tid & 15) * 4;
            const float4 v = *(const float4*)&W[((long)h * NFEAT_ + k0 + kr) * NHID_ + d];
            tile[kr][d] = v.x; tile[kr][d + 1] = v.y;
            tile[kr][d + 2] = v.z; tile[kr][d + 3] = v.w;
        }
        __syncthreads();
        #pragma unroll
        for (int p = 0; p < 4; ++p) {
            const int d = p * 16 + (tid >> 4), k = (tid & 15) * 4;
            ushort4 o;
            o.x = f2b(tile[k][d]);     o.y = f2b(tile[k + 1][d]);
            o.z = f2b(tile[k + 2][d]); o.w = f2b(tile[k + 3][d]);
            *(ushort4*)&WcT[((long)h * 64 + d) * NFEAT_ + k0 + k] = o;
        }
    }
}

// ---------------------------------------------------------------------------
// Sparse masked softmax + aggregation + ELU -> enc (bf16, [N, H*nhid]).
// One block per node n (512 threads = 8 waves, wave h = head h):
//   - neighbor list loaded into LDS once per node (shared by all heads)
//   - e_dst gathered from edT[m][h]: the 8 waves' reads of neighbor m hit
//     the SAME 32B line
//   - phase 2: the 8 waves collectively consume each full 1KB Whb row
// Softmax fp32-exact; 16 gathers in flight per wave (lists padded with
// p=0/m=0 => exactly-zero contribution).
// ---------------------------------------------------------------------------
__global__ __launch_bounds__(512) void attn_agg(
    const u16* __restrict__ Whb, const float* __restrict__ esrc,
    const float* __restrict__ edT, const int* __restrict__ cnt,
    const int* __restrict__ nbr, u16* __restrict__ enc)
{
    __shared__ __align__(16) int   mLds[MAXD];
    __shared__ __align__(16) float pLds[NHEADS_][MAXD];
    const int h = threadIdx.x >> 6, lane = threadIdx.x & 63;
    const int n = blockIdx.x;

    const int deg  = min(cnt[n], MAXD);
    const int degp = (deg + 15) & ~15;           // padded length (<= MAXD)

    // wave 0: stage neighbor list (+ zero padding) into LDS
    if (h == 0) {
        const int* lst = nbr + n * MAXD;
        for (int j = lane; j < deg; j += 64) mLds[j] = lst[j];
        for (int j = deg + lane; j < degp; j += 64) mLds[j] = 0;
    }
    __syncthreads();

    const float es = esrc[h * NNODES + n];

    float mymax = -3.4e38f;
    for (int j = lane; j < deg; j += 64) {
        float ev = es + edT[mLds[j] * NHEADS_ + h];
        ev = ev > 0.f ? ev : ALPHA_ * ev;
        pLds[h][j] = ev;
        mymax = fmaxf(mymax, ev);
    }
    for (int j = deg + lane; j < degp; j += 64) pLds[h][j] = 0.f;
    #pragma unroll
    for (int off = 32; off; off >>= 1) mymax = fmaxf(mymax, __shfl_xor(mymax, off));

    float mysum = 0.f;
    for (int j = lane; j < deg; j += 64) {
        const float p = __expf(pLds[h][j] - mymax);
        pLds[h][j] = p;
        mysum += p;
    }
    #pragma unroll
    for (int off = 32; off; off >>= 1) mysum += __shfl_xor(mysum, off);

    __syncthreads();

    // Phase 2: lane == output dim d within head h. 16 gathers in flight.
    float acc = 0.f;
    const u16* base = Whb + h * NHID_ + lane;
    for (int j0 = 0; j0 < degp; j0 += 16) {
        const int4   ma = *(const int4*)&mLds[j0];
        const int4   mb = *(const int4*)&mLds[j0 + 4];
        const int4   mc = *(const int4*)&mLds[j0 + 8];
        const int4   md = *(const int4*)&mLds[j0 + 12];
        const float4 pa = *(const float4*)&pLds[h][j0];
        const float4 pb = *(const float4*)&pLds[h][j0 + 4];
        const float4 pc = *(const float4*)&pLds[h][j0 + 8];
        const float4 pd = *(const float4*)&pLds[h][j0 + 12];
        const float v0  = b2f(base[(long)ma.x << 9]);
        const float v1  = b2f(base[(long)ma.y << 9]);
        const float v2  = b2f(base[(long)ma.z << 9]);
        const float v3  = b2f(base[(long)ma.w << 9]);
        const float v4  = b2f(base[(long)mb.x << 9]);
        const float v5  = b2f(base[(long)mb.y << 9]);
        const float v6  = b2f(base[(long)mb.z << 9]);
        const float v7  = b2f(base[(long)mb.w << 9]);
        const float v8  = b2f(base[(long)mc.x << 9]);
        const float v9  = b2f(base[(long)mc.y << 9]);
        const float v10 = b2f(base[(long)mc.z << 9]);
        const float v11 = b2f(base[(long)mc.w << 9]);
        const float v12 = b2f(base[(long)md.x << 9]);
        const float v13 = b2f(base[(long)md.y << 9]);
        const float v14 = b2f(base[(long)md.z << 9]);
        const float v15 = b2f(base[(long)md.w << 9]);
        acc = fmaf(pa.x, v0,  acc); acc = fmaf(pa.y, v1,  acc);
        acc = fmaf(pa.z, v2,  acc); acc = fmaf(pa.w, v3,  acc);
        acc = fmaf(pb.x, v4,  acc); acc = fmaf(pb.y, v5,  acc);
        acc = fmaf(pb.z, v6,  acc); acc = fmaf(pb.w, v7,  acc);
        acc = fmaf(pc.x, v8,  acc); acc = fmaf(pc.y, v9,  acc);
        acc = fmaf(pc.z, v10, acc); acc = fmaf(pc.w, v11, acc);
        acc = fmaf(pd.x, v12, acc); acc = fmaf(pd.y, v13, acc);
        acc = fmaf(pd.z, v14, acc); acc = fmaf(pd.w, v15, acc);
    }

    float hv = acc / mysum;
    hv = hv > 0.f ? hv : expm1f(hv);                       // ELU
    enc[(long)n * EMB_ + h * NHID_ + lane] = f2b(hv);
}

// ---------------------------------------------------------------------------
extern "C" void kernel_launch(void* const* d_in, const int* in_sizes, int n_in,
                              void* d_out, int out_size, void* d_ws, size_t ws_size,
                              hipStream_t stream)
{
    const float* x   = (const float*)d_in[0];
    const float* adj = (const float*)d_in[1];
    const float* W   = (const float*)d_in[2];
    const float* a1  = (const float*)d_in[3];
    const float* a2  = (const float*)d_in[4];
    const float* W1  = (const float*)d_in[5];
    const float* b1  = (const float*)d_in[6];
    const float* W2  = (const float*)d_in[7];
    const float* b2  = (const float*)d_in[8];
    const float* W3  = (const float*)d_in[9];
    const float* b3  = (const float*)d_in[10];
    const float* W4  = (const float*)d_in[11];
    const float* b4  = (const float*)d_in[12];
    float* out = (float*)d_out;

    // Workspace layout (16B-aligned offsets). dd1..dd3 alias xb (dead after
    // the head GEMM).
    float* es  = (float*)d_ws;                        //    32,768 f
    float* edT = es + 32768;                          //    32,768 f  [n][8]
    u16* Whb = (u16*)(edT + 32768);                   // 2,097,152 us (4 MB)
    u16* enc = Whb + 2097152;                         // 2,097,152 us
    u16* WcT = enc + 2097152;                         //   524,288 us
    u16* W1b = WcT + 524288;                          //   131,072 us
    u16* W2b = W1b + 131072;                          //    65,536 us
    u16* W3b = W2b + 65536;                           //   131,072 us
    u16* W4b = W3b + 131072;                          //   524,288 us
    int* cnt = (int*)(W4b + 524288);                  //     4,096 i
    int* nbr = cnt + 4096;                            // 1,048,576 i
    u16* xb  = (u16*)(nbr + 1048576);                 // 4,194,304 us (8 MB)
    u16* dd1 = xb;                                    // 1,048,576 us (alias)
    u16* dd2 = dd1 + 1048576;                         // 1,048,576 us
    u16* dd3 = dd2 + 1048576;                         // 2,097,152 us

    // 0) prep: bf16 casts + WcT transpose
    prep<<<dim3(CASTB + 128), 256, 0, stream>>>(
        x, W, W1, W2, W3, W4, xb, WcT, W1b, W2b, W3b, W4b);

    // 1) head GEMM (-> Whb + es/edT) fused with the adjacency scan:
    //    512 GEMM blocks first, 4096 nbr blocks overlap the GEMM.
    head_gemm_nbr<<<dim3(512 + NNODES), 256, 0, stream>>>(
        xb, WcT, Whb, a1, a2, es, edT, adj, cnt, nbr);

    // 2) sparse softmax + aggregate + ELU -> enc (bf16); block per node
    attn_agg<<<dim3(NNODES), 512, 0, stream>>>(Whb, es, edT, cnt, nbr, enc);

    // 3) decoder MLP (y = x @ W^T + b), bf16 MFMA, fp32 accum
    gemm_bt<64, 32, 1, 1><<<dim3(8, 64), 256, 0, stream>>>(
        enc, W1b, b1, dd1, NNODES, 256, 512);
    gemm_bt<64, 32, 1, 1><<<dim3(8, 64), 256, 0, stream>>>(
        dd1, W2b, b2, dd2, NNODES, 256, 256);
    gemm_bt<64, 64, 1, 1><<<dim3(8, 64), 256, 0, stream>>>(
        dd2, W3b, b3, dd3, NNODES, 512, 256);
    gemm_bt<64, 128, 0, 0><<<dim3(8, 64), 256, 0, stream>>>(
        dd3, W4b, b4, out, NNODES, 1024, 512);
}